// Round 1
// baseline (83.156 us; speedup 1.0000x reference)
//
#include <hip/hip_runtime.h>

// spatial_adaptive_operator: B=4, H=W=128, N=16384, C=128, P=4
// d_in: [0]=x (B,N,C) f32, [1]=deltaA (B,N,C) f32, [2]=H, [3]=W, [4]=Wo (8,C) f32, [5]=bo (8,) f32
// d_out: out (B,N,C) f32  ++  sampling_locations (B,N,1,1,P,2) f32

#define HW_ 128
#define CC_ 128
#define PP_ 4
#define NN_ (HW_ * HW_)

__global__ __launch_bounds__(256) void sao_kernel(
    const float* __restrict__ x,
    const float* __restrict__ dA,
    const float* __restrict__ Wo,
    const float* __restrict__ bo,
    float* __restrict__ out,
    float* __restrict__ locs)
{
    const int gtid = blockIdx.x * blockDim.x + threadIdx.x;
    const int wave = gtid >> 6;          // one wave per (b, n)
    const int lane = threadIdx.x & 63;   // lane owns channels {2*lane, 2*lane+1}
    const int b = wave >> 14;            // wave / 16384
    const int n = wave & (NN_ - 1);
    const int ix = n & (HW_ - 1);
    const int iy = n >> 7;

    const size_t rowbase = (size_t)(b * NN_ + n) * CC_ + 2 * lane;
    const float2 x2 = *(const float2*)(x + rowbase);
    const float2 d2 = *(const float2*)(dA + rowbase);

    // off[o] = dot(x_row, Wo[o]) + bo[o], o in [0,8)
    float off[8];
#pragma unroll
    for (int o = 0; o < 8; ++o) {
        const float2 w2 = *(const float2*)(Wo + o * CC_ + 2 * lane);
        off[o] = x2.x * w2.x + x2.y * w2.y;
    }
#pragma unroll
    for (int m = 32; m >= 1; m >>= 1) {
#pragma unroll
        for (int o = 0; o < 8; ++o)
            off[o] += __shfl_xor(off[o], m);
    }
#pragma unroll
    for (int o = 0; o < 8; ++o) off[o] += bo[o];

    const float refx = (ix + 0.5f) * (1.0f / HW_);
    const float refy = (iy + 0.5f) * (1.0f / HW_);

    // sampling_locations: 8 floats per point, layout (..., P, 2)
    if (lane < 8) {
        const float ref = (lane & 1) ? refy : refx;
        locs[(size_t)(b * NN_ + n) * 8 + lane] = ref + off[lane] * (1.0f / HW_);
    }

    float acc0 = 0.f, acc1 = 0.f;
#pragma unroll
    for (int p = 0; p < PP_; ++p) {
        // mirror reference arithmetic exactly (f32)
        const float locx = refx + off[2 * p] * (1.0f / HW_);
        const float locy = refy + off[2 * p + 1] * (1.0f / HW_);
        const float gx = 2.0f * locx - 1.0f;
        const float gy = 2.0f * locy - 1.0f;
        const float xp = ((gx + 1.0f) * (float)HW_ - 1.0f) * 0.5f;
        const float yp = ((gy + 1.0f) * (float)HW_ - 1.0f) * 0.5f;
        const float x0f = floorf(xp), y0f = floorf(yp);
        const float wx1 = xp - x0f, wy1 = yp - y0f;
        const float wx0 = 1.0f - wx1, wy0 = 1.0f - wy1;
        const int ix0 = (int)x0f, iy0 = (int)y0f;

        float feat0 = 0.f, feat1 = 0.f, wt0 = 0.f, wt1 = 0.f;
#pragma unroll
        for (int k = 0; k < 4; ++k) {
            const int cx = ix0 + (k & 1);
            const int cy = iy0 + (k >> 1);
            const bool valid = (cx >= 0) && (cx < HW_) && (cy >= 0) && (cy < HW_);
            float w = ((k & 1) ? wx1 : wx0) * ((k >> 1) ? wy1 : wy0);
            w = valid ? w : 0.0f;
            const int cxc = min(max(cx, 0), HW_ - 1);
            const int cyc = min(max(cy, 0), HW_ - 1);
            const size_t cb = ((size_t)b * NN_ + (size_t)(cyc * HW_ + cxc)) * CC_ + 2 * lane;
            const float2 xv = *(const float2*)(x + cb);
            const float2 dv = *(const float2*)(dA + cb);
            feat0 = fmaf(w, xv.x, feat0);
            feat1 = fmaf(w, xv.y, feat1);
            wt0 = fmaf(w, dv.x, wt0);
            wt1 = fmaf(w, dv.y, wt1);
        }
        acc0 = fmaf(feat0, wt0 - d2.x, acc0);
        acc1 = fmaf(feat1, wt1 - d2.y, acc1);
    }

    *(float2*)(out + rowbase) = make_float2(acc0 * 0.25f, acc1 * 0.25f);
}

extern "C" void kernel_launch(void* const* d_in, const int* in_sizes, int n_in,
                              void* d_out, int out_size, void* d_ws, size_t ws_size,
                              hipStream_t stream) {
    const float* x = (const float*)d_in[0];
    const float* dA = (const float*)d_in[1];
    const float* Wo = (const float*)d_in[4];
    const float* bo = (const float*)d_in[5];
    float* out = (float*)d_out;

    const int B = in_sizes[0] / (NN_ * CC_);            // 4
    float* locs = out + (size_t)B * NN_ * CC_;          // second tuple output

    const int waves = B * NN_;                           // one wave per point
    const int blocks = waves / 4;                        // 4 waves (256 thr) per block
    sao_kernel<<<blocks, 256, 0, stream>>>(x, dA, Wo, bo, out, locs);
}